// Round 7
// baseline (2134.055 us; speedup 1.0000x reference)
//
#include <hip/hip_runtime.h>
#include <hip/hip_bf16.h>
#include <hip/hip_cooperative_groups.h>
#include <math.h>

namespace cg = cooperative_groups;

#define N_NODES 50000
#define N_EDGES 800000
#define GK 256

typedef unsigned short US;
typedef __attribute__((ext_vector_type(8))) short short8;
typedef __attribute__((ext_vector_type(4))) float floatx4;
typedef __attribute__((address_space(1))) const void* gptr_t;
typedef __attribute__((address_space(3))) void* lptr_t;

static __device__ __forceinline__ float bflo(unsigned int u) {
  union { unsigned int i; float f; } c; c.i = u << 16; return c.f;
}
static __device__ __forceinline__ float bfhi(unsigned int u) {
  union { unsigned int i; float f; } c; c.i = u & 0xffff0000u; return c.f;
}
static __device__ __forceinline__ float bf2f(US u) {
  union { unsigned int i; float f; } c; c.i = ((unsigned int)u) << 16; return c.f;
}
static __device__ __forceinline__ US f2bf(float f) {  // round-to-nearest-even
  union { float f; unsigned int i; } c; c.f = f;
  unsigned int x = c.i;
  return (US)((x + 0x7fffu + ((x >> 16) & 1u)) >> 16);
}

struct MegaArgs {
  const float* x; const int* row; const int* col;
  const float* W1; const float* b1;
  const float* W2; const float* b2;
  const float* W3; const float* b3;
  const float* W4; const float* b4;
  float* outp;
  US* Ab; US* Bb; US* B64; US* Hfin;
  float* dinv; int* cnt; int* row_ptr; int* fill; int* bsums;
  int2* srcs2;
  US* Wt1; US* Wt2; US* Wt3; US* Wt4;
};

// ---------- phase: gemm256  C[M,256] = A[M,256] @ Wt[256,256]^T ----------
// M-tile 64/block, 4 waves = 64-col quadrants, BK=64, global_load_lds 16B,
// XOR-swizzled unpadded LDS (2-way alias = free).
static __device__ __forceinline__ void gemm256_phase(
    unsigned char* shmem, const US* A, const US* Wt, US* C) {
  US* As = (US*)shmem;            // 64x64  = 8 KB
  US* Bs = (US*)(shmem + 8192);   // 256x64 = 32 KB
  int tid = threadIdx.x;
  int lane = tid & 63;
  int w = tid >> 6;
  int wc = w * 64;
  int lm = lane & 15, lk = lane >> 4;
  int lr = lane >> 3, lc = lane & 7;
  int gc = lc ^ lr;
  const int ntiles = (N_NODES + 63) / 64;  // 782

  for (int tile = blockIdx.x; tile < ntiles; tile += gridDim.x) {
    int bm = tile * 64;
    floatx4 zero = {0.f, 0.f, 0.f, 0.f};
    floatx4 acc[4][4];
#pragma unroll
    for (int i = 0; i < 4; ++i)
#pragma unroll
      for (int j = 0; j < 4; ++j) acc[i][j] = zero;

    for (int k0 = 0; k0 < GK; k0 += 64) {
#pragma unroll
      for (int i = 0; i < 2; ++i) {
        int rbase = i * 32 + w * 8;
        int r = rbase + lr;
        const US* ga = A + (size_t)(bm + r) * GK + k0 + gc * 8;
        lptr_t la = (lptr_t)(void*)&As[rbase * 64];
        if (bm + r < N_NODES)
          __builtin_amdgcn_global_load_lds((gptr_t)(const void*)ga, la, 16, 0, 0);
      }
#pragma unroll
      for (int i = 0; i < 8; ++i) {
        int rbase = i * 32 + w * 8;
        int r = rbase + lr;
        const US* gb = Wt + (size_t)r * GK + k0 + gc * 8;
        lptr_t lb = (lptr_t)(void*)&Bs[rbase * 64];
        __builtin_amdgcn_global_load_lds((gptr_t)(const void*)gb, lb, 16, 0, 0);
      }
      __syncthreads();
#pragma unroll
      for (int s = 0; s < 2; ++s) {
        short8 af[4], bfr[4];
#pragma unroll
        for (int i = 0; i < 4; ++i) {
          int row = i * 16 + lm;
          int c = (s * 4 + lk) ^ (row & 7);
          af[i] = *(const short8*)&As[row * 64 + c * 8];
        }
#pragma unroll
        for (int j = 0; j < 4; ++j) {
          int row = wc + j * 16 + lm;
          int c = (s * 4 + lk) ^ (row & 7);
          bfr[j] = *(const short8*)&Bs[row * 64 + c * 8];
        }
#pragma unroll
        for (int i = 0; i < 4; ++i)
#pragma unroll
          for (int j = 0; j < 4; ++j)
            acc[i][j] = __builtin_amdgcn_mfma_f32_16x16x32_bf16(af[i], bfr[j], acc[i][j], 0, 0, 0);
      }
      __syncthreads();
    }
    // C/D layout: col = lane&15, row = (lane>>4)*4 + reg
#pragma unroll
    for (int i = 0; i < 4; ++i)
#pragma unroll
      for (int j = 0; j < 4; ++j) {
        int colg = wc + j * 16 + lm;
#pragma unroll
        for (int r = 0; r < 4; ++r) {
          int m = bm + i * 16 + lk * 4 + r;
          if (m < N_NODES) C[(size_t)m * 256 + colg] = f2bf(acc[i][j][r]);
        }
      }
  }
}

// ---------- phase: gemm64  C[M,64] = A[M,256] @ Wt3[64,256]^T ----------
static __device__ __forceinline__ void gemm64_phase(
    unsigned char* shmem, const US* A, const US* Wt, US* C) {
  US* As = (US*)shmem;             // 128x64 = 16 KB
  US* Bs = (US*)(shmem + 16384);   // 64x64  = 8 KB
  int tid = threadIdx.x;
  int lane = tid & 63;
  int w = tid >> 6;
  int wr = w * 32;
  int lm = lane & 15, lk = lane >> 4;
  int lr = lane >> 3, lc = lane & 7;
  int gc = lc ^ lr;
  const int ntiles = (N_NODES + 127) / 128;  // 391

  for (int tile = blockIdx.x; tile < ntiles; tile += gridDim.x) {
    int bm = tile * 128;
    floatx4 zero = {0.f, 0.f, 0.f, 0.f};
    floatx4 acc[2][4];
#pragma unroll
    for (int i = 0; i < 2; ++i)
#pragma unroll
      for (int j = 0; j < 4; ++j) acc[i][j] = zero;

    for (int k0 = 0; k0 < GK; k0 += 64) {
#pragma unroll
      for (int i = 0; i < 4; ++i) {
        int rbase = i * 32 + w * 8;
        int r = rbase + lr;
        const US* ga = A + (size_t)(bm + r) * GK + k0 + gc * 8;
        lptr_t la = (lptr_t)(void*)&As[rbase * 64];
        if (bm + r < N_NODES)
          __builtin_amdgcn_global_load_lds((gptr_t)(const void*)ga, la, 16, 0, 0);
      }
#pragma unroll
      for (int i = 0; i < 2; ++i) {
        int rbase = i * 32 + w * 8;
        int r = rbase + lr;
        const US* gb = Wt + (size_t)r * GK + k0 + gc * 8;
        lptr_t lb = (lptr_t)(void*)&Bs[rbase * 64];
        __builtin_amdgcn_global_load_lds((gptr_t)(const void*)gb, lb, 16, 0, 0);
      }
      __syncthreads();
#pragma unroll
      for (int s = 0; s < 2; ++s) {
        short8 af[2], bfr[4];
#pragma unroll
        for (int i = 0; i < 2; ++i) {
          int row = wr + i * 16 + lm;
          int c = (s * 4 + lk) ^ (row & 7);
          af[i] = *(const short8*)&As[row * 64 + c * 8];
        }
#pragma unroll
        for (int j = 0; j < 4; ++j) {
          int row = j * 16 + lm;
          int c = (s * 4 + lk) ^ (row & 7);
          bfr[j] = *(const short8*)&Bs[row * 64 + c * 8];
        }
#pragma unroll
        for (int i = 0; i < 2; ++i)
#pragma unroll
          for (int j = 0; j < 4; ++j)
            acc[i][j] = __builtin_amdgcn_mfma_f32_16x16x32_bf16(af[i], bfr[j], acc[i][j], 0, 0, 0);
      }
      __syncthreads();
    }
#pragma unroll
    for (int i = 0; i < 2; ++i)
#pragma unroll
      for (int j = 0; j < 4; ++j) {
        int colg = j * 16 + lm;
#pragma unroll
        for (int r = 0; r < 4; ++r) {
          int m = bm + wr + i * 16 + lk * 4 + r;
          if (m < N_NODES) C[(size_t)m * 64 + colg] = f2bf(acc[i][j][r]);
        }
      }
  }
}

// ---------- phase: agg256 (wave-per-node, byte-path-bound ~59us) ----------
static __device__ __forceinline__ void agg256_phase(
    const US* t, US* out, const int* row_ptr, const int* cnt,
    const int2* srcs2, const float* dinv, const float* bias) {
  int wv = threadIdx.x >> 6;
  int lane = threadIdx.x & 63;
  int base = lane * 4;
  for (int j = blockIdx.x * 4 + wv; j < N_NODES; j += gridDim.x * 4) {
    int start = row_ptr[j];
    int n = cnt[j];
    float a0 = 0.f, a1 = 0.f, a2 = 0.f, a3 = 0.f;
    int i = 0;
    for (; i + 3 < n; i += 4) {
      int2 e0 = srcs2[start + i + 0];
      int2 e1 = srcs2[start + i + 1];
      int2 e2 = srcs2[start + i + 2];
      int2 e3 = srcs2[start + i + 3];
      float w0 = __int_as_float(e0.y), w1 = __int_as_float(e1.y);
      float w2 = __int_as_float(e2.y), w3 = __int_as_float(e3.y);
      uint2 v0 = *(const uint2*)(t + (size_t)e0.x * 256 + base);
      uint2 v1 = *(const uint2*)(t + (size_t)e1.x * 256 + base);
      uint2 v2 = *(const uint2*)(t + (size_t)e2.x * 256 + base);
      uint2 v3 = *(const uint2*)(t + (size_t)e3.x * 256 + base);
      a0 += bflo(v0.x) * w0; a1 += bfhi(v0.x) * w0;
      a2 += bflo(v0.y) * w0; a3 += bfhi(v0.y) * w0;
      a0 += bflo(v1.x) * w1; a1 += bfhi(v1.x) * w1;
      a2 += bflo(v1.y) * w1; a3 += bfhi(v1.y) * w1;
      a0 += bflo(v2.x) * w2; a1 += bfhi(v2.x) * w2;
      a2 += bflo(v2.y) * w2; a3 += bfhi(v2.y) * w2;
      a0 += bflo(v3.x) * w3; a1 += bfhi(v3.x) * w3;
      a2 += bflo(v3.y) * w3; a3 += bfhi(v3.y) * w3;
    }
    for (; i < n; ++i) {
      int2 e = srcs2[start + i];
      float w0 = __int_as_float(e.y);
      uint2 v0 = *(const uint2*)(t + (size_t)e.x * 256 + base);
      a0 += bflo(v0.x) * w0; a1 += bfhi(v0.x) * w0;
      a2 += bflo(v0.y) * w0; a3 += bfhi(v0.y) * w0;
    }
    float dj = dinv[j];
    uint2 vj = *(const uint2*)(t + (size_t)j * 256 + base);
    float r0 = (a0 + bflo(vj.x) * dj) * dj + bias[base + 0];
    float r1 = (a1 + bfhi(vj.x) * dj) * dj + bias[base + 1];
    float r2 = (a2 + bflo(vj.y) * dj) * dj + bias[base + 2];
    float r3 = (a3 + bfhi(vj.y) * dj) * dj + bias[base + 3];
    r0 = fmaxf(r0, 0.f); r1 = fmaxf(r1, 0.f);
    r2 = fmaxf(r2, 0.f); r3 = fmaxf(r3, 0.f);
    unsigned int o0 = ((unsigned int)f2bf(r1) << 16) | f2bf(r0);
    unsigned int o1 = ((unsigned int)f2bf(r3) << 16) | f2bf(r2);
    *(uint2*)(out + (size_t)j * 256 + base) = make_uint2(o0, o1);
  }
}

static __device__ __forceinline__ void agg64_phase(
    const US* t, US* out, const int* row_ptr, const int* cnt,
    const int2* srcs2, const float* dinv, const float* bias) {
  int wv = threadIdx.x >> 6;
  int lane = threadIdx.x & 63;
  for (int j = blockIdx.x * 4 + wv; j < N_NODES; j += gridDim.x * 4) {
    int start = row_ptr[j];
    int n = cnt[j];
    float acc = 0.f;
    int i = 0;
    for (; i + 3 < n; i += 4) {
      int2 e0 = srcs2[start + i + 0];
      int2 e1 = srcs2[start + i + 1];
      int2 e2 = srcs2[start + i + 2];
      int2 e3 = srcs2[start + i + 3];
      acc += bf2f(t[(size_t)e0.x * 64 + lane]) * __int_as_float(e0.y);
      acc += bf2f(t[(size_t)e1.x * 64 + lane]) * __int_as_float(e1.y);
      acc += bf2f(t[(size_t)e2.x * 64 + lane]) * __int_as_float(e2.y);
      acc += bf2f(t[(size_t)e3.x * 64 + lane]) * __int_as_float(e3.y);
    }
    for (; i < n; ++i) {
      int2 e = srcs2[start + i];
      acc += bf2f(t[(size_t)e.x * 64 + lane]) * __int_as_float(e.y);
    }
    float dj = dinv[j];
    float r = (acc + bf2f(t[(size_t)j * 64 + lane]) * dj) * dj + bias[lane];
    out[(size_t)j * 64 + lane] = f2bf(r);
  }
}

// ---------- the mega-kernel ----------
__global__ __launch_bounds__(256, 4) void mega_kernel(MegaArgs a) {
  cg::grid_group gg = cg::this_grid();
  __shared__ __align__(16) unsigned char shmem[40960];
  const int tid = threadIdx.x;
  const int gtid = blockIdx.x * 256 + tid;
  const int gthreads = gridDim.x * 256;

  // P0: zero cnt + cvt x->bf16 + cvt all weights (independent writes)
  for (int i = gtid; i < N_NODES; i += gthreads) a.cnt[i] = 0;
  for (int i = gtid; i < N_NODES * 64; i += gthreads) {  // 3.2M elems / 4
    float4 v = *(const float4*)(a.x + (size_t)i * 4);
    US o[4] = { f2bf(v.x), f2bf(v.y), f2bf(v.z), f2bf(v.w) };
    *(ushort4*)(a.Ab + (size_t)i * 4) = *(ushort4*)o;
  }
  for (int idx = gtid; idx < 151552; idx += gthreads) {
    if (idx < 65536) {
      int k = idx >> 8, n = idx & 255;
      a.Wt1[n * 256 + k] = f2bf(a.W1[idx]);
    } else if (idx < 131072) {
      int i = idx - 65536, k = i >> 8, n = i & 255;
      a.Wt2[n * 256 + k] = f2bf(a.W2[i]);
    } else if (idx < 147456) {
      int i = idx - 131072, k = i >> 6, n = i & 63;
      a.Wt3[n * 256 + k] = f2bf(a.W3[i]);
    } else {
      int i = idx - 147456, k = i >> 6, n = i & 63;
      a.Wt4[n * 64 + k] = f2bf(a.W4[i]);
    }
  }
  gg.sync();

  // P1: in-degree histogram
  for (int e = gtid; e < N_EDGES; e += gthreads) atomicAdd(&a.cnt[a.col[e]], 1);
  gg.sync();

  // P2: block-level exclusive scan (196 virtual blocks) + dinv
  {
    int* s = (int*)shmem;
    const int nvb = (N_NODES + 255) / 256;  // 196
    for (int vb = blockIdx.x; vb < nvb; vb += gridDim.x) {
      int gid = vb * 256 + tid;
      int v = (gid < N_NODES) ? a.cnt[gid] : 0;
      if (gid < N_NODES) a.dinv[gid] = 1.0f / sqrtf((float)(v + 1));
      s[tid] = v;
      __syncthreads();
      for (int off = 1; off < 256; off <<= 1) {
        int t = (tid >= off) ? s[tid - off] : 0;
        __syncthreads();
        s[tid] += t;
        __syncthreads();
      }
      if (gid < N_NODES) a.row_ptr[gid] = s[tid] - v;
      if (tid == 255) a.bsums[vb] = s[255];
      __syncthreads();
    }
  }
  gg.sync();

  // P3: top-level scan of 196 block sums (block 0 only)
  if (blockIdx.x == 0) {
    int* s = (int*)shmem;
    const int nvb = (N_NODES + 255) / 256;
    int v = (tid < nvb) ? a.bsums[tid] : 0;
    s[tid] = v;
    __syncthreads();
    for (int off = 1; off < 256; off <<= 1) {
      int t = (tid >= off) ? s[tid - off] : 0;
      __syncthreads();
      s[tid] += t;
      __syncthreads();
    }
    if (tid < nvb) a.bsums[tid] = s[tid] - v;
  }
  gg.sync();

  // P4: add block offsets, copy fill cursors
  for (int i = gtid; i < N_NODES; i += gthreads) {
    int v = a.row_ptr[i] + a.bsums[i >> 8];
    a.row_ptr[i] = v;
    a.fill[i] = v;
  }
  gg.sync();

  // P5: CSR fill with packed (src, dinv[src])
  for (int e = gtid; e < N_EDGES; e += gthreads) {
    int d = a.col[e];
    int r = a.row[e];
    int pos = atomicAdd(&a.fill[d], 1);
    a.srcs2[pos] = make_int2(r, __float_as_int(a.dinv[r]));
  }
  gg.sync();

  // layers 1..5: gemm256 + agg256(relu)
  gemm256_phase(shmem, a.Ab, a.Wt1, a.Bb);
  gg.sync();
  agg256_phase(a.Bb, a.Ab, a.row_ptr, a.cnt, a.srcs2, a.dinv, a.b1);
  gg.sync();
  for (int l = 0; l < 4; ++l) {
    gemm256_phase(shmem, a.Ab, a.Wt2, a.Bb);
    gg.sync();
    agg256_phase(a.Bb, a.Ab, a.row_ptr, a.cnt, a.srcs2, a.dinv, a.b2);
    gg.sync();
  }

  // layer 6: gemm64 + agg64 (no relu)
  gemm64_phase(shmem, a.Ab, a.Wt3, a.B64);
  gg.sync();
  agg64_phase(a.B64, a.Hfin, a.row_ptr, a.cnt, a.srcs2, a.dinv, a.b3);
  gg.sync();

  // final dense: sigmoid(H @ W4t^T + b4), 16-row tiles per wave
  {
    int wv = tid >> 6, lane = tid & 63;
    int lm = lane & 15, lk = lane >> 4;
    const int ntiles = N_NODES / 16;  // 3125 exactly
    for (int t = blockIdx.x * 4 + wv; t < ntiles; t += gridDim.x * 4) {
      int m0 = t * 16;
      floatx4 zero = {0.f, 0.f, 0.f, 0.f};
      floatx4 acc[4] = {zero, zero, zero, zero};
#pragma unroll
      for (int ks = 0; ks < 2; ++ks) {
        short8 af = *(const short8*)&a.Hfin[(size_t)(m0 + lm) * 64 + ks * 32 + lk * 8];
#pragma unroll
        for (int jt = 0; jt < 4; ++jt) {
          short8 bf = *(const short8*)&a.Wt4[(size_t)(jt * 16 + lm) * 64 + ks * 32 + lk * 8];
          acc[jt] = __builtin_amdgcn_mfma_f32_16x16x32_bf16(af, bf, acc[jt], 0, 0, 0);
        }
      }
#pragma unroll
      for (int jt = 0; jt < 4; ++jt) {
        int colg = jt * 16 + lm;
        float bv = a.b4[colg];
#pragma unroll
        for (int r = 0; r < 4; ++r) {
          int m = m0 + lk * 4 + r;
          float v = acc[jt][r] + bv;
          a.outp[(size_t)m * 64 + colg] = 1.0f / (1.0f + expf(-v));
        }
      }
    }
  }
}

// ----------------- driver -----------------

extern "C" void kernel_launch(void* const* d_in, const int* in_sizes, int n_in,
                              void* d_out, int out_size, void* d_ws, size_t ws_size,
                              hipStream_t stream) {
  MegaArgs a;
  a.x  = (const float*)d_in[0];
  const int* ei = (const int*)d_in[1];
  a.row = ei;
  a.col = ei + N_EDGES;
  a.W1 = (const float*)d_in[2]; a.b1 = (const float*)d_in[3];
  a.W2 = (const float*)d_in[4]; a.b2 = (const float*)d_in[5];
  a.W3 = (const float*)d_in[6]; a.b3 = (const float*)d_in[7];
  a.W4 = (const float*)d_in[8]; a.b4 = (const float*)d_in[9];
  a.outp = (float*)d_out;

  const int N = N_NODES, E = N_EDGES;
  US* Ab = (US*)d_ws;
  US* Bb = Ab + (size_t)N * 256;
  US* B64 = Bb + (size_t)N * 256;
  US* Hfin = B64 + (size_t)N * 64;
  float* dinv = (float*)(Hfin + (size_t)N * 64);
  int* cnt = (int*)(dinv + N);
  int* row_ptr = cnt + N;
  int* fill = row_ptr + N;
  int* bsums = fill + N;
  int2* srcs2 = (int2*)(bsums + 256);
  US* Wt1 = (US*)(srcs2 + E);
  US* Wt2 = Wt1 + 256 * 256;
  US* Wt3 = Wt2 + 256 * 256;
  US* Wt4 = Wt3 + 64 * 256;
  a.Ab = Ab; a.Bb = Bb; a.B64 = B64; a.Hfin = Hfin;
  a.dinv = dinv; a.cnt = cnt; a.row_ptr = row_ptr; a.fill = fill; a.bsums = bsums;
  a.srcs2 = srcs2;
  a.Wt1 = Wt1; a.Wt2 = Wt2; a.Wt3 = Wt3; a.Wt4 = Wt4;

  // co-resident grid size: LDS 40 KB -> expect 4 blocks/CU -> 1024 blocks
  int maxb = 0;
  if (hipOccupancyMaxActiveBlocksPerMultiprocessor(&maxb, (const void*)mega_kernel, 256, 0)
          != hipSuccess || maxb <= 0)
    maxb = 2;  // conservative fallback (LDS guarantees >= 4, VGPR-capped >= 2)
  int grid = maxb * 256;
  if (grid > 1024) grid = 1024;

  void* kp[] = { (void*)&a };
  hipLaunchCooperativeKernel((void*)mega_kernel, dim3(grid), dim3(256), kp, 0, stream);
}

// Round 8
// 759.184 us; speedup vs baseline: 2.8110x; 2.8110x over previous
//
#include <hip/hip_runtime.h>
#include <hip/hip_bf16.h>
#include <math.h>

#define N_NODES 50000
#define N_EDGES 800000
#define GK 256

typedef unsigned short US;
typedef __attribute__((ext_vector_type(8))) short short8;
typedef __attribute__((ext_vector_type(4))) float floatx4;
typedef __attribute__((address_space(1))) const void* gptr_t;
typedef __attribute__((address_space(3))) void* lptr_t;

static __device__ __forceinline__ float bflo(unsigned int u) {
  union { unsigned int i; float f; } c; c.i = u << 16; return c.f;
}
static __device__ __forceinline__ float bfhi(unsigned int u) {
  union { unsigned int i; float f; } c; c.i = u & 0xffff0000u; return c.f;
}
static __device__ __forceinline__ float bf2f(US u) {
  union { unsigned int i; float f; } c; c.i = ((unsigned int)u) << 16; return c.f;
}
static __device__ __forceinline__ US f2bf(float f) {  // round-to-nearest-even
  union { float f; unsigned int i; } c; c.f = f;
  unsigned int x = c.i;
  return (US)((x + 0x7fffu + ((x >> 16) & 1u)) >> 16);
}

// ----------------- preprocessing -----------------

// fused: in-degree histogram + x->bf16 + all weight transposes (independent work)
__global__ void pre0_kernel(const int* __restrict__ col, int* __restrict__ cnt,
                            const float* __restrict__ x, US* __restrict__ xb,
                            const float* __restrict__ W1, const float* __restrict__ W2,
                            const float* __restrict__ W3, const float* __restrict__ W4,
                            US* __restrict__ Wt1, US* __restrict__ Wt2,
                            US* __restrict__ Wt3, US* __restrict__ Wt4) {
  int gt = blockIdx.x * 256 + threadIdx.x;
  int gs = gridDim.x * 256;
  for (int e = gt; e < N_EDGES; e += gs) atomicAdd(&cnt[col[e]], 1);
  for (int i = gt; i < N_NODES * 64; i += gs) {   // x: 12.8M elems / 4
    float4 v = *(const float4*)(x + (size_t)i * 4);
    US o[4] = { f2bf(v.x), f2bf(v.y), f2bf(v.z), f2bf(v.w) };
    *(ushort4*)(xb + (size_t)i * 4) = *(ushort4*)o;
  }
  for (int idx = gt; idx < 151552; idx += gs) {
    if (idx < 65536) {
      int k = idx >> 8, n = idx & 255;
      Wt1[n * 256 + k] = f2bf(W1[idx]);
    } else if (idx < 131072) {
      int i = idx - 65536, k = i >> 8, n = i & 255;
      Wt2[n * 256 + k] = f2bf(W2[i]);
    } else if (idx < 147456) {
      int i = idx - 131072, k = i >> 6, n = i & 63;
      Wt3[n * 256 + k] = f2bf(W3[i]);
    } else {
      int i = idx - 147456, k = i >> 6, n = i & 63;
      Wt4[n * 64 + k] = f2bf(W4[i]);
    }
  }
}

__global__ void scan_block_kernel(const int* __restrict__ in, int* __restrict__ out,
                                  int* __restrict__ bsums, float* __restrict__ dinv, int n) {
  __shared__ int s[256];
  int gid = blockIdx.x * 256 + threadIdx.x;
  int v = (gid < n) ? in[gid] : 0;
  if (gid < n) dinv[gid] = 1.0f / sqrtf((float)(v + 1));  // +1 self-loop
  s[threadIdx.x] = v;
  __syncthreads();
  for (int off = 1; off < 256; off <<= 1) {
    int t = (threadIdx.x >= off) ? s[threadIdx.x - off] : 0;
    __syncthreads();
    s[threadIdx.x] += t;
    __syncthreads();
  }
  if (gid < n) out[gid] = s[threadIdx.x] - v;  // exclusive
  if (threadIdx.x == 255) bsums[blockIdx.x] = s[255];
}

__global__ void scan_top_kernel(int* __restrict__ bsums, int n) {
  __shared__ int s[256];
  int v = (threadIdx.x < n) ? bsums[threadIdx.x] : 0;
  s[threadIdx.x] = v;
  __syncthreads();
  for (int off = 1; off < 256; off <<= 1) {
    int t = (threadIdx.x >= off) ? s[threadIdx.x - off] : 0;
    __syncthreads();
    s[threadIdx.x] += t;
    __syncthreads();
  }
  if (threadIdx.x < n) bsums[threadIdx.x] = s[threadIdx.x] - v;
}

__global__ void scan_add_kernel(int* __restrict__ row_ptr, int* __restrict__ fill,
                                const int* __restrict__ bsums, int n) {
  int gid = blockIdx.x * 256 + threadIdx.x;
  if (gid < n) {
    int v = row_ptr[gid] + bsums[blockIdx.x];
    row_ptr[gid] = v;
    fill[gid] = v;
  }
}

__global__ void fill_kernel(const int* __restrict__ row, const int* __restrict__ col,
                            int* __restrict__ fill, int2* __restrict__ srcs2,
                            const float* __restrict__ dinv, int E) {
  int e = blockIdx.x * blockDim.x + threadIdx.x;
  if (e < E) {
    int d = col[e];
    int r = row[e];
    int pos = atomicAdd(&fill[d], 1);
    srcs2[pos] = make_int2(r, __float_as_int(dinv[r]));
  }
}

// ----------------- gemm256 (layer 1: x@W1), R6 structure -----------------

__global__ __launch_bounds__(256) void gemm256_kernel(
    const US* __restrict__ A, const US* __restrict__ Wt,
    US* __restrict__ C, int M) {
  __shared__ __align__(16) US As[64 * 64];    // 8 KB
  __shared__ __align__(16) US Bs[256 * 64];   // 32 KB
  int tid = threadIdx.x;
  int bm = blockIdx.x * 64;
  int lane = tid & 63;
  int w = tid >> 6;
  int wc = w * 64;
  int lm = lane & 15, lk = lane >> 4;
  int lr = lane >> 3, lc = lane & 7;
  int gc = lc ^ lr;

  floatx4 zero = {0.f, 0.f, 0.f, 0.f};
  floatx4 acc[4][4];
#pragma unroll
  for (int i = 0; i < 4; ++i)
#pragma unroll
    for (int j = 0; j < 4; ++j) acc[i][j] = zero;

  for (int k0 = 0; k0 < GK; k0 += 64) {
#pragma unroll
    for (int i = 0; i < 2; ++i) {
      int rbase = i * 32 + w * 8;
      int r = rbase + lr;
      const US* ga = A + (size_t)(bm + r) * GK + k0 + gc * 8;
      lptr_t la = (lptr_t)(void*)&As[rbase * 64];
      if (bm + r < M)
        __builtin_amdgcn_global_load_lds((gptr_t)(const void*)ga, la, 16, 0, 0);
    }
#pragma unroll
    for (int i = 0; i < 8; ++i) {
      int rbase = i * 32 + w * 8;
      int r = rbase + lr;
      const US* gb = Wt + (size_t)r * GK + k0 + gc * 8;
      lptr_t lb = (lptr_t)(void*)&Bs[rbase * 64];
      __builtin_amdgcn_global_load_lds((gptr_t)(const void*)gb, lb, 16, 0, 0);
    }
    __syncthreads();
#pragma unroll
    for (int s = 0; s < 2; ++s) {
      short8 af[4], bfr[4];
#pragma unroll
      for (int i = 0; i < 4; ++i) {
        int row = i * 16 + lm;
        int c = (s * 4 + lk) ^ (row & 7);
        af[i] = *(const short8*)&As[row * 64 + c * 8];
      }
#pragma unroll
      for (int j = 0; j < 4; ++j) {
        int row = wc + j * 16 + lm;
        int c = (s * 4 + lk) ^ (row & 7);
        bfr[j] = *(const short8*)&Bs[row * 64 + c * 8];
      }
#pragma unroll
      for (int i = 0; i < 4; ++i)
#pragma unroll
        for (int j = 0; j < 4; ++j)
          acc[i][j] = __builtin_amdgcn_mfma_f32_16x16x32_bf16(af[i], bfr[j], acc[i][j], 0, 0, 0);
    }
    __syncthreads();
  }
#pragma unroll
  for (int i = 0; i < 4; ++i)
#pragma unroll
    for (int j = 0; j < 4; ++j) {
      int colg = wc + j * 16 + lm;
#pragma unroll
      for (int r = 0; r < 4; ++r) {
        int m = bm + i * 16 + lk * 4 + r;
        if (m < M) C[(size_t)m * 256 + colg] = f2bf(acc[i][j][r]);
      }
    }
}

// ----------------- fused layer: G_out = (relu(agg(G_in)+bias)) @ Wt^T -----------------
// Block = 32 destination nodes. Phase 1: each wave aggs 8 nodes (512B row gathers,
// fp32 acc) -> bias/relu -> bf16 -> XOR-swizzled LDS A-tile [32][256].
// Phase 2: MFMA A-tile @ Wt, B-fragments read DIRECTLY from global (Wt is
// L2-resident, 128/16 KB) -> no K-loop barriers, one __syncthreads total.
// A chunk swizzle: 16B chunk c of row r stored at slot (c&~7)|((c^r)&7).

template <int NC_OUT>   // 256 (Wt2) or 64 (Wt3); gather width is always 256
__global__ __launch_bounds__(256, 5) void fused_layer_kernel(
    const US* __restrict__ G_in, const US* __restrict__ Wt,
    const float* __restrict__ bias,
    const int* __restrict__ row_ptr, const int* __restrict__ cnt,
    const int2* __restrict__ srcs2, const float* __restrict__ dinv,
    US* __restrict__ G_out) {
  __shared__ __align__(16) US As[32 * 256];   // 16 KB
  int tid = threadIdx.x, lane = tid & 63, w = tid >> 6;
  int bm = blockIdx.x * 32;

  // ---- phase 1: gather/aggregate 8 nodes per wave ----
  {
    int base = lane * 4;
    float b0 = bias[base + 0], b1 = bias[base + 1];
    float b2 = bias[base + 2], b3 = bias[base + 3];
    int cch = lane >> 1;                       // 16B chunk holding this lane's 4 cols
    int coff = (lane & 1) * 4;                 // elem offset within chunk
#pragma unroll 1
    for (int q = 0; q < 8; ++q) {
      int lr = w * 8 + q;
      int j = bm + lr;
      if (j < N_NODES) {
        int start = row_ptr[j];
        int n = cnt[j];
        float a0 = 0.f, a1 = 0.f, a2 = 0.f, a3 = 0.f;
        int i = 0;
        for (; i + 3 < n; i += 4) {
          int2 e0 = srcs2[start + i + 0];
          int2 e1 = srcs2[start + i + 1];
          int2 e2 = srcs2[start + i + 2];
          int2 e3 = srcs2[start + i + 3];
          float w0 = __int_as_float(e0.y), w1 = __int_as_float(e1.y);
          float w2 = __int_as_float(e2.y), w3 = __int_as_float(e3.y);
          uint2 v0 = *(const uint2*)(G_in + (size_t)e0.x * 256 + base);
          uint2 v1 = *(const uint2*)(G_in + (size_t)e1.x * 256 + base);
          uint2 v2 = *(const uint2*)(G_in + (size_t)e2.x * 256 + base);
          uint2 v3 = *(const uint2*)(G_in + (size_t)e3.x * 256 + base);
          a0 += bflo(v0.x) * w0; a1 += bfhi(v0.x) * w0;
          a2 += bflo(v0.y) * w0; a3 += bfhi(v0.y) * w0;
          a0 += bflo(v1.x) * w1; a1 += bfhi(v1.x) * w1;
          a2 += bflo(v1.y) * w1; a3 += bfhi(v1.y) * w1;
          a0 += bflo(v2.x) * w2; a1 += bfhi(v2.x) * w2;
          a2 += bflo(v2.y) * w2; a3 += bfhi(v2.y) * w2;
          a0 += bflo(v3.x) * w3; a1 += bfhi(v3.x) * w3;
          a2 += bflo(v3.y) * w3; a3 += bfhi(v3.y) * w3;
        }
        for (; i < n; ++i) {
          int2 e = srcs2[start + i];
          float w0 = __int_as_float(e.y);
          uint2 v0 = *(const uint2*)(G_in + (size_t)e.x * 256 + base);
          a0 += bflo(v0.x) * w0; a1 += bfhi(v0.x) * w0;
          a2 += bflo(v0.y) * w0; a3 += bfhi(v0.y) * w0;
        }
        float dj = dinv[j];
        uint2 vj = *(const uint2*)(G_in + (size_t)j * 256 + base);
        float r0 = (a0 + bflo(vj.x) * dj) * dj + b0;
        float r1 = (a1 + bfhi(vj.x) * dj) * dj + b1;
        float r2 = (a2 + bflo(vj.y) * dj) * dj + b2;
        float r3 = (a3 + bfhi(vj.y) * dj) * dj + b3;
        r0 = fmaxf(r0, 0.f); r1 = fmaxf(r1, 0.f);   // all fused layers have ReLU
        r2 = fmaxf(r2, 0.f); r3 = fmaxf(r3, 0.f);
        unsigned int o0 = ((unsigned int)f2bf(r1) << 16) | f2bf(r0);
        unsigned int o1 = ((unsigned int)f2bf(r3) << 16) | f2bf(r2);
        int slot = (cch & ~7) | ((cch ^ lr) & 7);
        *(uint2*)&As[lr * 256 + slot * 8 + coff] = make_uint2(o0, o1);
      }
    }
  }
  __syncthreads();

  // ---- phase 2: [32 x 256] @ Wt[NC_OUT x 256]^T, B direct from L2 ----
  {
    constexpr int NJ = NC_OUT / 64;            // 16-col tiles per wave
    int lm = lane & 15, lk = lane >> 4;
    int wc = w * 16 * NJ;
    floatx4 zero = {0.f, 0.f, 0.f, 0.f};
    floatx4 acc[2][NJ];
#pragma unroll
    for (int i = 0; i < 2; ++i)
#pragma unroll
      for (int j = 0; j < NJ; ++j) acc[i][j] = zero;

#pragma unroll
    for (int ks = 0; ks < 8; ++ks) {
      short8 af[2];
#pragma unroll
      for (int i = 0; i < 2; ++i) {
        int row = i * 16 + lm;
        int c = ks * 4 + lk;
        int slot = (c & ~7) | ((c ^ row) & 7);
        af[i] = *(const short8*)&As[row * 256 + slot * 8];
      }
#pragma unroll
      for (int j = 0; j < NJ; ++j) {
        short8 bf = *(const short8*)&Wt[(size_t)(wc + j * 16 + lm) * 256 + ks * 32 + lk * 8];
#pragma unroll
        for (int i = 0; i < 2; ++i)
          acc[i][j] = __builtin_amdgcn_mfma_f32_16x16x32_bf16(af[i], bf, acc[i][j], 0, 0, 0);
      }
    }
    // C/D: col = lane&15, row = (lane>>4)*4 + reg
#pragma unroll
    for (int i = 0; i < 2; ++i)
#pragma unroll
      for (int j = 0; j < NJ; ++j) {
        int colg = wc + j * 16 + lm;
#pragma unroll
        for (int r = 0; r < 4; ++r) {
          int m = bm + i * 16 + lk * 4 + r;
          if (m < N_NODES) G_out[(size_t)m * NC_OUT + colg] = f2bf(acc[i][j][r]);
        }
      }
  }
}

// ----------------- fused final: out = sigmoid((agg64(G6)+b3) @ W4t^T + b4) -----------------
// Block = 32 nodes; wave aggs 8 nodes (64-col rows, scalar/lane) -> LDS A[32][64]
// (XOR swizzle), then MFMA vs Wt4 (L1-resident 8 KB) + bias + sigmoid -> fp32 out.

__global__ __launch_bounds__(256) void fused_final_kernel(
    const US* __restrict__ G_in, const US* __restrict__ Wt4,
    const float* __restrict__ b3, const float* __restrict__ b4,
    const int* __restrict__ row_ptr, const int* __restrict__ cnt,
    const int2* __restrict__ srcs2, const float* __restrict__ dinv,
    float* __restrict__ outp) {
  __shared__ __align__(16) US As[32 * 64];    // 4 KB
  int tid = threadIdx.x, lane = tid & 63, w = tid >> 6;
  int bm = blockIdx.x * 32;

  {
    float bb = b3[lane];
    int cch = lane >> 3, coff = lane & 7;
#pragma unroll 1
    for (int q = 0; q < 8; ++q) {
      int lr = w * 8 + q;
      int j = bm + lr;
      if (j < N_NODES) {
        int start = row_ptr[j];
        int n = cnt[j];
        float acc = 0.f;
        int i = 0;
        for (; i + 3 < n; i += 4) {
          int2 e0 = srcs2[start + i + 0];
          int2 e1 = srcs2[start + i + 1];
          int2 e2 = srcs2[start + i + 2];
          int2 e3 = srcs2[start + i + 3];
          acc += bf2f(G_in[(size_t)e0.x * 64 + lane]) * __int_as_float(e0.y);
          acc += bf2f(G_in[(size_t)e1.x * 64 + lane]) * __int_as_float(e1.y);
          acc += bf2f(G_in[(size_t)e2.x * 64 + lane]) * __int_as_float(e2.y);
          acc += bf2f(G_in[(size_t)e3.x * 64 + lane]) * __int_as_float(e3.y);
        }
        for (; i < n; ++i) {
          int2 e = srcs2[start + i];
          acc += bf2f(G_in[(size_t)e.x * 64 + lane]) * __int_as_float(e.y);
        }
        float dj = dinv[j];
        float r = (acc + bf2f(G_in[(size_t)j * 64 + lane]) * dj) * dj + bb;  // no relu
        int slot = cch ^ (lr & 7);
        As[lr * 64 + slot * 8 + coff] = f2bf(r);
      }
    }
  }
  __syncthreads();

  {
    int lm = lane & 15, lk = lane >> 4;
    int wc = w * 16;
    floatx4 zero = {0.f, 0.f, 0.f, 0.f};
    floatx4 acc[2] = {zero, zero};
#pragma unroll
    for (int ks = 0; ks < 2; ++ks) {
      short8 af[2];
#pragma unroll
      for (int i = 0; i < 2; ++i) {
        int row = i * 16 + lm;
        int c = ks * 4 + lk;
        int slot = c ^ (row & 7);
        af[i] = *(const short8*)&As[row * 64 + slot * 8];
      }
      short8 bf = *(const short8*)&Wt4[(size_t)(wc + lm) * 64 + ks * 32 + lk * 8];
#pragma unroll
      for (int i = 0; i < 2; ++i)
        acc[i] = __builtin_amdgcn_mfma_f32_16x16x32_bf16(af[i], bf, acc[i], 0, 0, 0);
    }
    int colg = wc + lm;
    float bv = b4[colg];
#pragma unroll
    for (int i = 0; i < 2; ++i)
#pragma unroll
      for (int r = 0; r < 4; ++r) {
        int m = bm + i * 16 + lk * 4 + r;
        if (m < N_NODES) {
          float v = acc[i][r] + bv;
          outp[(size_t)m * 64 + colg] = 1.0f / (1.0f + expf(-v));
        }
      }
  }
}

// ----------------- driver -----------------

extern "C" void kernel_launch(void* const* d_in, const int* in_sizes, int n_in,
                              void* d_out, int out_size, void* d_ws, size_t ws_size,
                              hipStream_t stream) {
  const float* x  = (const float*)d_in[0];
  const int* ei   = (const int*)d_in[1];
  const float* W1 = (const float*)d_in[2];
  const float* b1 = (const float*)d_in[3];
  const float* W2 = (const float*)d_in[4];
  const float* b2 = (const float*)d_in[5];
  const float* W3 = (const float*)d_in[6];
  const float* b3 = (const float*)d_in[7];
  const float* W4 = (const float*)d_in[8];
  const float* b4 = (const float*)d_in[9];
  float* outp = (float*)d_out;

  const int N = N_NODES, E = N_EDGES;
  const int* row = ei;
  const int* col = ei + E;

  US* Ab = (US*)d_ws;                         // [N,256] bf16 (x, then G ping)
  US* Bb = Ab + (size_t)N * 256;              // [N,256] bf16 (G pong)
  US* B64 = Bb + (size_t)N * 256;             // [N,64]  (G6)
  US* Hfin = B64 + (size_t)N * 64;            // (unused, kept for layout stability)
  float* dinv = (float*)(Hfin + (size_t)N * 64);
  int* cnt = (int*)(dinv + N);
  int* row_ptr = cnt + N;
  int* fill = row_ptr + N;
  int* bsums = fill + N;                      // [256]
  int2* srcs2 = (int2*)(bsums + 256);         // [E]
  US* Wt1 = (US*)(srcs2 + E);                 // [256,256]
  US* Wt2 = Wt1 + 256 * 256;
  US* Wt3 = Wt2 + 256 * 256;                  // [64,256]
  US* Wt4 = Wt3 + 64 * 256;                   // [64,64]

  hipMemsetAsync(cnt, 0, N * sizeof(int), stream);
  pre0_kernel<<<1024, 256, 0, stream>>>(col, cnt, x, Ab, W1, W2, W3, W4,
                                        Wt1, Wt2, Wt3, Wt4);
  int nblk = (N + 255) / 256;
  scan_block_kernel<<<nblk, 256, 0, stream>>>(cnt, row_ptr, bsums, dinv, N);
  scan_top_kernel<<<1, 256, 0, stream>>>(bsums, nblk);
  scan_add_kernel<<<nblk, 256, 0, stream>>>(row_ptr, fill, bsums, N);
  fill_kernel<<<(E + 255) / 256, 256, 0, stream>>>(row, col, fill, srcs2, dinv, E);

  int gf = (N + 31) / 32;  // 1563 fused blocks

  // G1 = x @ W1
  gemm256_kernel<<<(N + 63) / 64, 256, 0, stream>>>(Ab, Wt1, Bb, N);
  // G2 = relu(agg(G1)+b1) @ W2
  fused_layer_kernel<256><<<gf, 256, 0, stream>>>(Bb, Wt2, b1, row_ptr, cnt, srcs2, dinv, Ab);
  // G3..G5 = relu(agg(.)+b2) @ W2
  fused_layer_kernel<256><<<gf, 256, 0, stream>>>(Ab, Wt2, b2, row_ptr, cnt, srcs2, dinv, Bb);
  fused_layer_kernel<256><<<gf, 256, 0, stream>>>(Bb, Wt2, b2, row_ptr, cnt, srcs2, dinv, Ab);
  fused_layer_kernel<256><<<gf, 256, 0, stream>>>(Ab, Wt2, b2, row_ptr, cnt, srcs2, dinv, Bb);
  // G6 = relu(agg(G5)+b2) @ W3   (256 -> 64)
  fused_layer_kernel<64><<<gf, 256, 0, stream>>>(Bb, Wt3, b2, row_ptr, cnt, srcs2, dinv, B64);
  // out = sigmoid((agg(G6)+b3) @ W4 + b4)
  fused_final_kernel<<<gf, 256, 0, stream>>>(B64, Wt4, b3, b4, row_ptr, cnt, srcs2, dinv, outp);
}

// Round 10
// 615.739 us; speedup vs baseline: 3.4658x; 1.2330x over previous
//
#include <hip/hip_runtime.h>
#include <hip/hip_bf16.h>
#include <math.h>

#define N_NODES 50000
#define N_EDGES 800000
#define GK 256

typedef unsigned short US;
typedef __attribute__((ext_vector_type(8))) short short8;
typedef __attribute__((ext_vector_type(4))) float floatx4;
typedef __attribute__((address_space(1))) const void* gptr_t;
typedef __attribute__((address_space(3))) void* lptr_t;

static __device__ __forceinline__ float bflo(unsigned int u) {
  union { unsigned int i; float f; } c; c.i = u << 16; return c.f;
}
static __device__ __forceinline__ float bfhi(unsigned int u) {
  union { unsigned int i; float f; } c; c.i = u & 0xffff0000u; return c.f;
}
static __device__ __forceinline__ float bf2f(US u) {
  union { unsigned int i; float f; } c; c.i = ((unsigned int)u) << 16; return c.f;
}
static __device__ __forceinline__ US f2bf(float f) {  // round-to-nearest-even
  union { float f; unsigned int i; } c; c.f = f;
  unsigned int x = c.i;
  return (US)((x + 0x7fffu + ((x >> 16) & 1u)) >> 16);
}

// ----------------- preprocessing -----------------

// fused: in-degree histogram + x->bf16 + all weight transposes
__global__ void pre0_kernel(const int* __restrict__ col, int* __restrict__ cnt,
                            const float* __restrict__ x, US* __restrict__ xb,
                            const float* __restrict__ W1, const float* __restrict__ W2,
                            const float* __restrict__ W3, const float* __restrict__ W4,
                            US* __restrict__ Wt1, US* __restrict__ Wt2,
                            US* __restrict__ Wt3, US* __restrict__ Wt4) {
  int gt = blockIdx.x * 256 + threadIdx.x;
  int gs = gridDim.x * 256;
  for (int e = gt; e < N_EDGES; e += gs) atomicAdd(&cnt[col[e]], 1);
  for (int i = gt; i < N_NODES * 64; i += gs) {   // x: 12.8M elems / 4
    float4 v = *(const float4*)(x + (size_t)i * 4);
    US o[4] = { f2bf(v.x), f2bf(v.y), f2bf(v.z), f2bf(v.w) };
    *(ushort4*)(xb + (size_t)i * 4) = *(ushort4*)o;
  }
  for (int idx = gt; idx < 151552; idx += gs) {
    if (idx < 65536) {
      int k = idx >> 8, n = idx & 255;
      Wt1[n * 256 + k] = f2bf(W1[idx]);
    } else if (idx < 131072) {
      int i = idx - 65536, k = i >> 8, n = i & 255;
      Wt2[n * 256 + k] = f2bf(W2[i]);
    } else if (idx < 147456) {
      int i = idx - 131072, k = i >> 6, n = i & 63;
      Wt3[n * 256 + k] = f2bf(W3[i]);
    } else {
      int i = idx - 147456, k = i >> 6, n = i & 63;
      Wt4[n * 64 + k] = f2bf(W4[i]);
    }
  }
}

__global__ void scan_block_kernel(const int* __restrict__ in, int* __restrict__ out,
                                  int* __restrict__ bsums, float* __restrict__ dinv, int n) {
  __shared__ int s[256];
  int gid = blockIdx.x * 256 + threadIdx.x;
  int v = (gid < n) ? in[gid] : 0;
  if (gid < n) dinv[gid] = 1.0f / sqrtf((float)(v + 1));  // +1 self-loop
  s[threadIdx.x] = v;
  __syncthreads();
  for (int off = 1; off < 256; off <<= 1) {
    int t = (threadIdx.x >= off) ? s[threadIdx.x - off] : 0;
    __syncthreads();
    s[threadIdx.x] += t;
    __syncthreads();
  }
  if (gid < n) out[gid] = s[threadIdx.x] - v;  // exclusive
  if (threadIdx.x == 255) bsums[blockIdx.x] = s[255];
}

__global__ void scan_top_kernel(int* __restrict__ bsums, int n) {
  __shared__ int s[256];
  int v = (threadIdx.x < n) ? bsums[threadIdx.x] : 0;
  s[threadIdx.x] = v;
  __syncthreads();
  for (int off = 1; off < 256; off <<= 1) {
    int t = (threadIdx.x >= off) ? s[threadIdx.x - off] : 0;
    __syncthreads();
    s[threadIdx.x] += t;
    __syncthreads();
  }
  if (threadIdx.x < n) bsums[threadIdx.x] = s[threadIdx.x] - v;
}

__global__ void scan_add_kernel(int* __restrict__ row_ptr, int* __restrict__ fill,
                                const int* __restrict__ bsums, int n) {
  int gid = blockIdx.x * 256 + threadIdx.x;
  if (gid < n) {
    int v = row_ptr[gid] + bsums[blockIdx.x];
    row_ptr[gid] = v;
    fill[gid] = v;
  }
}

__global__ void fill_kernel(const int* __restrict__ row, const int* __restrict__ col,
                            int* __restrict__ fill, int2* __restrict__ srcs2,
                            const float* __restrict__ dinv, int E) {
  int e = blockIdx.x * blockDim.x + threadIdx.x;
  if (e < E) {
    int d = col[e];
    int r = row[e];
    int pos = atomicAdd(&fill[d], 1);
    srcs2[pos] = make_int2(r, __float_as_int(dinv[r]));
  }
}

// ----------------- gemm256: C[M,256] = A[M,256] @ Wt[256,256]^T -----------------
// M-tile 64, 4 waves = 64-col quadrants, BK=64, global_load_lds 16B, XOR swizzle.
// Epilogue: C-tile staged in LDS (pad +16 cols) -> 16B/lane coalesced stores.

__global__ __launch_bounds__(256) void gemm256_kernel(
    const US* __restrict__ A, const US* __restrict__ Wt,
    US* __restrict__ C, int M) {
  __shared__ __align__(16) US shm[20480];     // 40 KB: staging (As+Bs) / C-tile
  US* As = shm;                                // 64x64   = 4096 US
  US* Bs = shm + 4096;                         // 256x64  = 16384 US
  int tid = threadIdx.x;
  int bm = blockIdx.x * 64;
  int lane = tid & 63;
  int w = tid >> 6;
  int wc = w * 64;
  int lm = lane & 15, lk = lane >> 4;
  int lr = lane >> 3, lc = lane & 7;
  int gc = lc ^ lr;

  floatx4 zero = {0.f, 0.f, 0.f, 0.f};
  floatx4 acc[4][4];
#pragma unroll
  for (int i = 0; i < 4; ++i)
#pragma unroll
    for (int j = 0; j < 4; ++j) acc[i][j] = zero;

  for (int k0 = 0; k0 < GK; k0 += 64) {
#pragma unroll
    for (int i = 0; i < 2; ++i) {
      int rbase = i * 32 + w * 8;
      int r = rbase + lr;
      const US* ga = A + (size_t)(bm + r) * GK + k0 + gc * 8;
      lptr_t la = (lptr_t)(void*)&As[rbase * 64];
      if (bm + r < M)
        __builtin_amdgcn_global_load_lds((gptr_t)(const void*)ga, la, 16, 0, 0);
    }
#pragma unroll
    for (int i = 0; i < 8; ++i) {
      int rbase = i * 32 + w * 8;
      int r = rbase + lr;
      const US* gb = Wt + (size_t)r * GK + k0 + gc * 8;
      lptr_t lb = (lptr_t)(void*)&Bs[rbase * 64];
      __builtin_amdgcn_global_load_lds((gptr_t)(const void*)gb, lb, 16, 0, 0);
    }
    __syncthreads();
#pragma unroll
    for (int s = 0; s < 2; ++s) {
      short8 af[4], bfr[4];
#pragma unroll
      for (int i = 0; i < 4; ++i) {
        int row = i * 16 + lm;
        int c = (s * 4 + lk) ^ (row & 7);
        af[i] = *(const short8*)&As[row * 64 + c * 8];
      }
#pragma unroll
      for (int j = 0; j < 4; ++j) {
        int row = wc + j * 16 + lm;
        int c = (s * 4 + lk) ^ (row & 7);
        bfr[j] = *(const short8*)&Bs[row * 64 + c * 8];
      }
#pragma unroll
      for (int i = 0; i < 4; ++i)
#pragma unroll
        for (int j = 0; j < 4; ++j)
          acc[i][j] = __builtin_amdgcn_mfma_f32_16x16x32_bf16(af[i], bfr[j], acc[i][j], 0, 0, 0);
    }
    __syncthreads();
  }

  // epilogue: LDS stage (64 rows x 256 cols, pad 16) -> coalesced 16B stores
  {
    constexpr int LDC = 272;
    US* Cs = shm;                              // 64*272 = 17408 US <= 20480
#pragma unroll
    for (int i = 0; i < 4; ++i)
#pragma unroll
      for (int j = 0; j < 4; ++j) {
        int colg = wc + j * 16 + lm;
#pragma unroll
        for (int r = 0; r < 4; ++r)
          Cs[(i * 16 + lk * 4 + r) * LDC + colg] = f2bf(acc[i][j][r]);
      }
    __syncthreads();
#pragma unroll
    for (int c = 0; c < 8; ++c) {              // 2048 = 64 rows x 32 chunks
      int idx = tid + c * 256;
      int row = idx >> 5;
      int ch = idx & 31;
      uint4 v = *(const uint4*)&Cs[row * LDC + ch * 8];
      if (bm + row < M) *(uint4*)&C[(size_t)(bm + row) * 256 + ch * 8] = v;
    }
  }
}

// ----------------- gemm64: C[M,64] = A[M,256] @ Wt3[64,256]^T -----------------

__global__ __launch_bounds__(256) void gemm64_kernel(
    const US* __restrict__ A, const US* __restrict__ Wt,
    US* __restrict__ C, int M) {
  __shared__ __align__(16) US shm[12288];     // 24 KB staging / C-tile
  US* As = shm;                                // 128x64 = 8192 US
  US* Bs = shm + 8192;                         // 64x64  = 4096 US
  int tid = threadIdx.x;
  int bm = blockIdx.x * 128;
  int lane = tid & 63;
  int w = tid >> 6;
  int wr = w * 32;
  int lm = lane & 15, lk = lane >> 4;
  int lr = lane >> 3, lc = lane & 7;
  int gc = lc ^ lr;

  floatx4 zero = {0.f, 0.f, 0.f, 0.f};
  floatx4 acc[2][4];
#pragma unroll
  for (int i = 0; i < 2; ++i)
#pragma unroll
    for (int j = 0; j < 4; ++j) acc[i][j] = zero;

  for (int k0 = 0; k0 < GK; k0 += 64) {
#pragma unroll
    for (int i = 0; i < 4; ++i) {
      int rbase = i * 32 + w * 8;
      int r = rbase + lr;
      const US* ga = A + (size_t)(bm + r) * GK + k0 + gc * 8;
      lptr_t la = (lptr_t)(void*)&As[rbase * 64];
      if (bm + r < M)
        __builtin_amdgcn_global_load_lds((gptr_t)(const void*)ga, la, 16, 0, 0);
    }
#pragma unroll
    for (int i = 0; i < 2; ++i) {
      int rbase = i * 32 + w * 8;
      int r = rbase + lr;
      const US* gb = Wt + (size_t)r * GK + k0 + gc * 8;
      lptr_t lb = (lptr_t)(void*)&Bs[rbase * 64];
      __builtin_amdgcn_global_load_lds((gptr_t)(const void*)gb, lb, 16, 0, 0);
    }
    __syncthreads();
#pragma unroll
    for (int s = 0; s < 2; ++s) {
      short8 af[2], bfr[4];
#pragma unroll
      for (int i = 0; i < 2; ++i) {
        int row = wr + i * 16 + lm;
        int c = (s * 4 + lk) ^ (row & 7);
        af[i] = *(const short8*)&As[row * 64 + c * 8];
      }
#pragma unroll
      for (int j = 0; j < 4; ++j) {
        int row = j * 16 + lm;
        int c = (s * 4 + lk) ^ (row & 7);
        bfr[j] = *(const short8*)&Bs[row * 64 + c * 8];
      }
#pragma unroll
      for (int i = 0; i < 2; ++i)
#pragma unroll
        for (int j = 0; j < 4; ++j)
          acc[i][j] = __builtin_amdgcn_mfma_f32_16x16x32_bf16(af[i], bfr[j], acc[i][j], 0, 0, 0);
    }
    __syncthreads();
  }

  // epilogue: LDS stage (128 rows x 64 cols, pad 8) -> coalesced 16B stores
  {
    constexpr int LDC = 72;
    US* Cs = shm;                              // 128*72 = 9216 US
#pragma unroll
    for (int i = 0; i < 2; ++i)
#pragma unroll
      for (int j = 0; j < 4; ++j) {
        int colg = j * 16 + lm;
#pragma unroll
        for (int r = 0; r < 4; ++r)
          Cs[(wr + i * 16 + lk * 4 + r) * LDC + colg] = f2bf(acc[i][j][r]);
      }
    __syncthreads();
    // FIX (R9 bug): full row = 8 chunks of 16B; 1024 slots = 128 rows x 8 chunks.
    // R9 had c<2 / row=idx>>2 / ch=idx&3 -> only cols 0..31 written, cols 32..63
    // left as poison -> absmax 1.95e-2.
#pragma unroll
    for (int c = 0; c < 4; ++c) {
      int idx = tid + c * 256;
      int row = idx >> 3;       // 0..127
      int ch = idx & 7;         // 0..7
      uint4 v = *(const uint4*)&Cs[row * LDC + ch * 8];
      if (bm + row < M) *(uint4*)&C[(size_t)(bm + row) * 64 + ch * 8] = v;
    }
  }
}

// ----------------- pull aggregation: one wave per node (fabric-floored ~59us) -----------------

template <bool RELU>
__global__ __launch_bounds__(64) void agg256_kernel(
    const US* __restrict__ t, US* __restrict__ out,
    const int* __restrict__ row_ptr, const int* __restrict__ cnt,
    const int2* __restrict__ srcs2, const float* __restrict__ dinv,
    const float* __restrict__ bias) {
  int j = blockIdx.x;
  int lane = threadIdx.x;
  int base = lane * 4;
  int start = row_ptr[j];
  int n = cnt[j];
  float a0 = 0.f, a1 = 0.f, a2 = 0.f, a3 = 0.f;
  int i = 0;
  for (; i + 3 < n; i += 4) {
    int2 e0 = srcs2[start + i + 0];
    int2 e1 = srcs2[start + i + 1];
    int2 e2 = srcs2[start + i + 2];
    int2 e3 = srcs2[start + i + 3];
    float w0 = __int_as_float(e0.y), w1 = __int_as_float(e1.y);
    float w2 = __int_as_float(e2.y), w3 = __int_as_float(e3.y);
    uint2 v0 = *(const uint2*)(t + (size_t)e0.x * 256 + base);
    uint2 v1 = *(const uint2*)(t + (size_t)e1.x * 256 + base);
    uint2 v2 = *(const uint2*)(t + (size_t)e2.x * 256 + base);
    uint2 v3 = *(const uint2*)(t + (size_t)e3.x * 256 + base);
    a0 += bflo(v0.x) * w0; a1 += bfhi(v0.x) * w0;
    a2 += bflo(v0.y) * w0; a3 += bfhi(v0.y) * w0;
    a0 += bflo(v1.x) * w1; a1 += bfhi(v1.x) * w1;
    a2 += bflo(v1.y) * w1; a3 += bfhi(v1.y) * w1;
    a0 += bflo(v2.x) * w2; a1 += bfhi(v2.x) * w2;
    a2 += bflo(v2.y) * w2; a3 += bfhi(v2.y) * w2;
    a0 += bflo(v3.x) * w3; a1 += bfhi(v3.x) * w3;
    a2 += bflo(v3.y) * w3; a3 += bfhi(v3.y) * w3;
  }
  for (; i < n; ++i) {
    int2 e = srcs2[start + i];
    float w0 = __int_as_float(e.y);
    uint2 v0 = *(const uint2*)(t + (size_t)e.x * 256 + base);
    a0 += bflo(v0.x) * w0; a1 += bfhi(v0.x) * w0;
    a2 += bflo(v0.y) * w0; a3 += bfhi(v0.y) * w0;
  }
  float dj = dinv[j];
  uint2 vj = *(const uint2*)(t + (size_t)j * 256 + base);
  float r0 = (a0 + bflo(vj.x) * dj) * dj + bias[base + 0];
  float r1 = (a1 + bfhi(vj.x) * dj) * dj + bias[base + 1];
  float r2 = (a2 + bflo(vj.y) * dj) * dj + bias[base + 2];
  float r3 = (a3 + bfhi(vj.y) * dj) * dj + bias[base + 3];
  if (RELU) {
    r0 = fmaxf(r0, 0.f); r1 = fmaxf(r1, 0.f);
    r2 = fmaxf(r2, 0.f); r3 = fmaxf(r3, 0.f);
  }
  unsigned int o0 = ((unsigned int)f2bf(r1) << 16) | f2bf(r0);
  unsigned int o1 = ((unsigned int)f2bf(r3) << 16) | f2bf(r2);
  *(uint2*)(out + (size_t)j * 256 + base) = make_uint2(o0, o1);
}

__global__ __launch_bounds__(64) void agg64_kernel(
    const US* __restrict__ t, US* __restrict__ out,
    const int* __restrict__ row_ptr, const int* __restrict__ cnt,
    const int2* __restrict__ srcs2, const float* __restrict__ dinv,
    const float* __restrict__ bias) {
  int j = blockIdx.x;
  int lane = threadIdx.x;
  int start = row_ptr[j];
  int n = cnt[j];
  float acc = 0.f;
  int i = 0;
  for (; i + 3 < n; i += 4) {
    int2 e0 = srcs2[start + i + 0];
    int2 e1 = srcs2[start + i + 1];
    int2 e2 = srcs2[start + i + 2];
    int2 e3 = srcs2[start + i + 3];
    acc += bf2f(t[(size_t)e0.x * 64 + lane]) * __int_as_float(e0.y);
    acc += bf2f(t[(size_t)e1.x * 64 + lane]) * __int_as_float(e1.y);
    acc += bf2f(t[(size_t)e2.x * 64 + lane]) * __int_as_float(e2.y);
    acc += bf2f(t[(size_t)e3.x * 64 + lane]) * __int_as_float(e3.y);
  }
  for (; i < n; ++i) {
    int2 e = srcs2[start + i];
    acc += bf2f(t[(size_t)e.x * 64 + lane]) * __int_as_float(e.y);
  }
  float dj = dinv[j];
  float r = (acc + bf2f(t[(size_t)j * 64 + lane]) * dj) * dj + bias[lane];
  out[(size_t)j * 64 + lane] = f2bf(r);
}

// ----------------- final dense: sigmoid(H[N,64] @ W4t^T + b4), MFMA -----------------

__global__ __launch_bounds__(256) void final_mfma_kernel(
    const US* __restrict__ H, const US* __restrict__ W4t,
    const float* __restrict__ b4, float* __restrict__ out, int M) {
  int wv = threadIdx.x >> 6, lane = threadIdx.x & 63;
  int m0 = blockIdx.x * 64 + wv * 16;
  if (m0 >= M) return;
  int lm = lane & 15, lk = lane >> 4;

  floatx4 zero = {0.f, 0.f, 0.f, 0.f};
  floatx4 acc[4] = {zero, zero, zero, zero};
#pragma unroll
  for (int ks = 0; ks < 2; ++ks) {
    short8 af = *(const short8*)&H[(size_t)(m0 + lm) * 64 + ks * 32 + lk * 8];
#pragma unroll
    for (int jt = 0; jt < 4; ++jt) {
      short8 bf = *(const short8*)&W4t[(size_t)(jt * 16 + lm) * 64 + ks * 32 + lk * 8];
      acc[jt] = __builtin_amdgcn_mfma_f32_16x16x32_bf16(af, bf, acc[jt], 0, 0, 0);
    }
  }
#pragma unroll
  for (int jt = 0; jt < 4; ++jt) {
    int col = jt * 16 + lm;
    float bv = b4[col];
#pragma unroll
    for (int r = 0; r < 4; ++r) {
      int m = m0 + lk * 4 + r;
      float v = acc[jt][r] + bv;
      out[(size_t)m * 64 + col] = 1.0f / (1.0f + expf(-v));
    }
  }
}

// ----------------- driver -----------------

extern "C" void kernel_launch(void* const* d_in, const int* in_sizes, int n_in,
                              void* d_out, int out_size, void* d_ws, size_t ws_size,
                              hipStream_t stream) {
  const float* x  = (const float*)d_in[0];
  const int* ei   = (const int*)d_in[1];
  const float* W1 = (const float*)d_in[2];
  const float* b1 = (const float*)d_in[3];
  const float* W2 = (const float*)d_in[4];
  const float* b2 = (const float*)d_in[5];
  const float* W3 = (const float*)d_in[6];
  const float* b3 = (const float*)d_in[7];
  const float* W4 = (const float*)d_in[8];
  const float* b4 = (const float*)d_in[9];
  float* outp = (float*)d_out;

  const int N = N_NODES, E = N_EDGES;
  const int* row = ei;
  const int* col = ei + E;

  US* Ab = (US*)d_ws;                         // [N,256] bf16 ping
  US* Bb = Ab + (size_t)N * 256;              // [N,256] bf16 pong
  US* B64 = Bb + (size_t)N * 256;             // [N,64] (layer-6 GEMM out)
  US* Hfin = B64 + (size_t)N * 64;            // [N,64] (final GEMM in)
  float* dinv = (float*)(Hfin + (size_t)N * 64);
  int* cnt = (int*)(dinv + N);
  int* row_ptr = cnt + N;
  int* fill = row_ptr + N;
  int* bsums = fill + N;                      // [256]
  int2* srcs2 = (int2*)(bsums + 256);         // [E]
  US* Wt1 = (US*)(srcs2 + E);                 // [256,256]
  US* Wt2 = Wt1 + 256 * 256;
  US* Wt3 = Wt2 + 256 * 256;                  // [64,256]
  US* Wt4 = Wt3 + 64 * 256;                   // [64,64]

  hipMemsetAsync(cnt, 0, N * sizeof(int), stream);
  pre0_kernel<<<1024, 256, 0, stream>>>(col, cnt, x, Ab, W1, W2, W3, W4,
                                        Wt1, Wt2, Wt3, Wt4);
  int nblk = (N + 255) / 256;
  scan_block_kernel<<<nblk, 256, 0, stream>>>(cnt, row_ptr, bsums, dinv, N);
  scan_top_kernel<<<1, 256, 0, stream>>>(bsums, nblk);
  scan_add_kernel<<<nblk, 256, 0, stream>>>(row_ptr, fill, bsums, N);
  fill_kernel<<<(E + 255) / 256, 256, 0, stream>>>(row, col, fill, srcs2, dinv, E);

  gemm256_kernel<<<(N + 63) / 64, 256, 0, stream>>>(Ab, Wt1, Bb, N);
  agg256_kernel<true><<<N, 64, 0, stream>>>(Bb, Ab, row_ptr, cnt, srcs2, dinv, b1);
  for (int l = 0; l < 4; ++l) {
    gemm256_kernel<<<(N + 63) / 64, 256, 0, stream>>>(Ab, Wt2, Bb, N);
    agg256_kernel<true><<<N, 64, 0, stream>>>(Bb, Ab, row_ptr, cnt, srcs2, dinv, b2);
  }
  gemm64_kernel<<<(N + 127) / 128, 256, 0, stream>>>(Ab, Wt3, B64, N);
  agg64_kernel<<<N, 64, 0, stream>>>(B64, Hfin, row_ptr, cnt, srcs2, dinv, b3);
  final_mfma_kernel<<<(N + 63) / 64, 256, 0, stream>>>(Hfin, Wt4, b4, outp, N);
}